// Round 1
// baseline (311.566 us; speedup 1.0000x reference)
//
#include <hip/hip_runtime.h>
#include <float.h>

#define D 128
#define CH 32          // rows staged per chunk (16 KB LDS)
#define NTHREADS 256

__launch_bounds__(NTHREADS, 2)
__global__ void gap_kernel(const float* __restrict__ feat,
                           const float* __restrict__ Wg,
                           const float* __restrict__ bg,
                           const int* __restrict__ seg_ids,
                           float* __restrict__ out,
                           int N)
{
    __shared__ float s_feat[CH][D];   // 16 KB staged rows
    __shared__ float s_gate[CH];
    __shared__ float s_e[CH];
    __shared__ float s_acc[D];

    const int seg = blockIdx.x;
    const int t = threadIdx.x;

    // ---- segment boundaries via lower_bound (uniform across all threads) ----
    int lo = 0, hi = N;
    while (lo < hi) { int mid = (lo + hi) >> 1; if (seg_ids[mid] < seg) lo = mid + 1; else hi = mid; }
    const int start = lo;
    hi = N;
    while (lo < hi) { int mid = (lo + hi) >> 1; if (seg_ids[mid] < seg + 1) lo = mid + 1; else hi = mid; }
    const int end = lo;
    const int n = end - start;

    if (n <= 0) {
        if (t < D) out[(size_t)seg * D + t] = 0.0f;
        return;
    }

    const int wave = t >> 6;
    const int lane = t & 63;
    const int half = lane >> 5;   // which row of the pair this half-wave handles
    const int l    = lane & 31;   // lane within half: owns cols 4l..4l+3

    // per-lane W fragment for the gate dot
    const float4 w4 = *reinterpret_cast<const float4*>(Wg + 4 * l);
    const float bias = bg[0];

    float m_old = -FLT_MAX;   // running max   (uniform across threads)
    float ssum  = 0.0f;       // running denom (uniform across threads)
    float acc   = 0.0f;       // this thread's column partial
    const int c    = t & (D - 1);  // owned column
    const int rpar = t >> 7;       // row parity (0: even rows, 1: odd rows)

    for (int base = 0; base < n; base += CH) {
        int rem = n - base; if (rem > CH) rem = CH;

        // ---- gate pass: wave w owns rows 8w..8w+7; halves take row pairs ----
        float4 f[4];
        #pragma unroll
        for (int i = 0; i < 4; ++i) {
            int r = 8 * wave + 2 * i + half;
            if (r < rem)
                f[i] = *reinterpret_cast<const float4*>(
                    feat + (size_t)(start + base + r) * D + 4 * l);
        }
        #pragma unroll
        for (int i = 0; i < 4; ++i) {
            int r = 8 * wave + 2 * i + half;
            if (r < rem) {
                *reinterpret_cast<float4*>(&s_feat[r][4 * l]) = f[i];
                float p = f[i].x * w4.x + f[i].y * w4.y + f[i].z * w4.z + f[i].w * w4.w;
                // reduce within each 32-lane half (masks <=16 never cross halves)
                #pragma unroll
                for (int m = 16; m >= 1; m >>= 1)
                    p += __shfl_xor(p, m, 64);
                if (l == 0) s_gate[r] = p + bias;
            }
        }
        __syncthreads();

        // ---- online softmax update (uniform scalar math on every thread) ----
        float m_new = m_old;
        for (int r = 0; r < rem; ++r) m_new = fmaxf(m_new, s_gate[r]);

        if (t < rem) s_e[t] = __expf(s_gate[t] - m_new);
        __syncthreads();

        float s_chunk = 0.0f;
        for (int r = 0; r < rem; ++r) s_chunk += s_e[r];

        const float scale = __expf(m_old - m_new);  // 0 on first chunk (m_old = -FLT_MAX)
        ssum = ssum * scale + s_chunk;
        acc *= scale;

        // ---- weighted accumulate from LDS copy (feat read from HBM once) ----
        for (int r = rpar; r < rem; r += 2)
            acc += s_e[r] * s_feat[r][c];

        __syncthreads();   // protect LDS before next chunk overwrites
        m_old = m_new;
    }

    // ---- combine the two row-parity halves, normalize, store ----
    if (t >= D) s_acc[c] = acc;
    __syncthreads();
    if (t < D) {
        float total = acc + s_acc[c];
        out[(size_t)seg * D + c] = total / ssum;
    }
}

extern "C" void kernel_launch(void* const* d_in, const int* in_sizes, int n_in,
                              void* d_out, int out_size, void* d_ws, size_t ws_size,
                              hipStream_t stream) {
    const float* feat = (const float*)d_in[0];
    const float* Wg   = (const float*)d_in[1];
    const float* bg   = (const float*)d_in[2];
    const int*   seg  = (const int*)d_in[3];
    float*       out  = (float*)d_out;

    const int N = in_sizes[3];          // number of nodes
    const int B = out_size / D;         // number of segments

    gap_kernel<<<B, NTHREADS, 0, stream>>>(feat, Wg, bg, seg, out, N);
}

// Round 2
// 207.033 us; speedup vs baseline: 1.5049x; 1.5049x over previous
//
#include <hip/hip_runtime.h>
#include <float.h>

#define D 128
#define NT 256

// Precompute segment start offsets: starts[s] = lower_bound(seg_ids, s), starts[B] = N.
__global__ __launch_bounds__(NT) void seg_starts_kernel(const int* __restrict__ seg_ids,
                                                        int* __restrict__ starts,
                                                        int N, int B) {
    int s = blockIdx.x * blockDim.x + threadIdx.x;
    if (s > B) return;
    if (s == B) { starts[B] = N; return; }
    int lo = 0, hi = N;
    while (lo < hi) { int mid = (lo + hi) >> 1; if (seg_ids[mid] < s) lo = mid + 1; else hi = mid; }
    starts[s] = lo;
}

// One wave per segment. Lane owns 2 columns. No LDS, no barriers.
__global__ __launch_bounds__(NT, 8) void gap_wave_kernel(const float* __restrict__ feat,
                                                         const float* __restrict__ Wg,
                                                         const float* __restrict__ bg,
                                                         const int* __restrict__ seg_ids,
                                                         const int* __restrict__ starts,
                                                         float* __restrict__ out,
                                                         int N, int B) {
    const int wid  = threadIdx.x >> 6;
    const int lane = threadIdx.x & 63;
    const int seg  = blockIdx.x * 4 + wid;
    if (seg >= B) return;

    int start, end;
    if (starts) {
        start = starts[seg];
        end   = starts[seg + 1];
    } else {
        // fallback: own binary searches (wave-uniform)
        int lo = 0, hi = N;
        while (lo < hi) { int mid = (lo + hi) >> 1; if (seg_ids[mid] < seg) lo = mid + 1; else hi = mid; }
        start = lo;
        hi = N;
        while (lo < hi) { int mid = (lo + hi) >> 1; if (seg_ids[mid] < seg + 1) lo = mid + 1; else hi = mid; }
        end = lo;
    }

    const float2 w   = *reinterpret_cast<const float2*>(Wg + 2 * lane);
    const float bias = bg[0];

    float m_run = -FLT_MAX, s_run = 0.0f;
    float accx = 0.0f, accy = 0.0f;

    const float* rowp = feat + (size_t)start * D + 2 * lane;

    int r = start;
    for (; r + 8 <= end; r += 8) {
        float2 f[8];
        #pragma unroll
        for (int i = 0; i < 8; ++i)
            f[i] = *reinterpret_cast<const float2*>(rowp + (size_t)i * D);

        float g[8];
        #pragma unroll
        for (int i = 0; i < 8; ++i) {
            float p = f[i].x * w.x + f[i].y * w.y;
            #pragma unroll
            for (int m = 32; m >= 1; m >>= 1)
                p += __shfl_xor(p, m, 64);
            g[i] = p + bias;
        }

        float bmax = g[0];
        #pragma unroll
        for (int i = 1; i < 8; ++i) bmax = fmaxf(bmax, g[i]);
        const float m_new = fmaxf(m_run, bmax);
        const float scale = __expf(m_run - m_new);   // 0 on first batch
        m_run = m_new;
        s_run *= scale; accx *= scale; accy *= scale;

        #pragma unroll
        for (int i = 0; i < 8; ++i) {
            const float e = __expf(g[i] - m_new);
            s_run += e;
            accx = fmaf(e, f[i].x, accx);
            accy = fmaf(e, f[i].y, accy);
        }
        rowp += 8 * D;
    }

    // remainder rows
    for (; r < end; ++r) {
        const float2 f = *reinterpret_cast<const float2*>(rowp);
        float p = f.x * w.x + f.y * w.y;
        #pragma unroll
        for (int m = 32; m >= 1; m >>= 1)
            p += __shfl_xor(p, m, 64);
        const float g = p + bias;
        const float m_new = fmaxf(m_run, g);
        const float scale = __expf(m_run - m_new);
        m_run = m_new;
        const float e = __expf(g - m_new);
        s_run = s_run * scale + e;
        accx = fmaf(e, f.x, accx * scale);
        accy = fmaf(e, f.y, accy * scale);
        rowp += D;
    }

    float2 o;
    if (end > start) {
        o.x = accx / s_run;
        o.y = accy / s_run;
    } else {
        o.x = 0.0f; o.y = 0.0f;   // empty segment -> zeros
    }
    *reinterpret_cast<float2*>(out + (size_t)seg * D + 2 * lane) = o;
}

extern "C" void kernel_launch(void* const* d_in, const int* in_sizes, int n_in,
                              void* d_out, int out_size, void* d_ws, size_t ws_size,
                              hipStream_t stream) {
    const float* feat = (const float*)d_in[0];
    const float* Wg   = (const float*)d_in[1];
    const float* bg   = (const float*)d_in[2];
    const int*   seg  = (const int*)d_in[3];
    float*       out  = (float*)d_out;

    const int N = in_sizes[3];      // nodes
    const int B = out_size / D;     // segments

    int* starts = nullptr;
    if (ws_size >= (size_t)(B + 1) * sizeof(int)) {
        starts = (int*)d_ws;
        seg_starts_kernel<<<(B + 1 + NT - 1) / NT, NT, 0, stream>>>(seg, starts, N, B);
    }

    const int segs_per_block = 4;   // one wave each
    gap_wave_kernel<<<(B + segs_per_block - 1) / segs_per_block, NT, 0, stream>>>(
        feat, Wg, bg, seg, starts, out, N, B);
}

// Round 3
// 200.665 us; speedup vs baseline: 1.5527x; 1.0317x over previous
//
#include <hip/hip_runtime.h>
#include <float.h>

#define D 128
#define NT 256

// Precompute segment start offsets: starts[s] = lower_bound(seg_ids, s), starts[B] = N.
__global__ __launch_bounds__(NT) void seg_starts_kernel(const int* __restrict__ seg_ids,
                                                        int* __restrict__ starts,
                                                        int N, int B) {
    int s = blockIdx.x * blockDim.x + threadIdx.x;
    if (s > B) return;
    if (s == B) { starts[B] = N; return; }
    int lo = 0, hi = N;
    while (lo < hi) { int mid = (lo + hi) >> 1; if (seg_ids[mid] < s) lo = mid + 1; else hi = mid; }
    starts[s] = lo;
}

// One wave per segment. Lane l: row-parity hr = l>>5, cols 4*(l&31)..+3 (float4).
// Each 32-lane half keeps an independent online-softmax state over its row parity;
// flash-style combine across halves at the end. No LDS, no barriers.
__global__ __launch_bounds__(NT, 8) void gap_wave_kernel(const float* __restrict__ feat,
                                                         const float* __restrict__ Wg,
                                                         const float* __restrict__ bg,
                                                         const int* __restrict__ starts,
                                                         float* __restrict__ out,
                                                         int B) {
    const int wid  = threadIdx.x >> 6;
    const int lane = threadIdx.x & 63;
    const int seg  = blockIdx.x * 4 + wid;
    if (seg >= B) return;

    const int hr = lane >> 5;        // row parity this half-wave owns
    const int c4 = lane & 31;        // column group: cols 4*c4 .. 4*c4+3

    const int start = starts[seg];
    const int end   = starts[seg + 1];
    const int n     = end - start;

    if (n <= 0) {
        if (hr == 0) {
            float4 z = {0.f, 0.f, 0.f, 0.f};
            *reinterpret_cast<float4*>(out + (size_t)seg * D + 4 * c4) = z;
        }
        return;
    }

    const float4 w4  = *reinterpret_cast<const float4*>(Wg + 4 * c4);
    const float bias = bg[0];

    float m_run = -FLT_MAX, s_run = 0.0f;
    float4 acc = {0.f, 0.f, 0.f, 0.f};

    // my half's row pointer: rows start+hr, start+hr+2, ...
    const float* rowp = feat + (size_t)(start + hr) * D + 4 * c4;

    int r = start;
    // ---- main loop: 8 rows / iter (4 rows per half), 4 x 16B loads ----
    for (; r + 8 <= end; r += 8) {
        float4 f[4];
        #pragma unroll
        for (int i = 0; i < 4; ++i)
            f[i] = *reinterpret_cast<const float4*>(rowp + (size_t)(2 * i) * D);

        float g[4];
        #pragma unroll
        for (int i = 0; i < 4; ++i) {
            float p = f[i].x * w4.x + f[i].y * w4.y + f[i].z * w4.z + f[i].w * w4.w;
            #pragma unroll
            for (int m = 16; m >= 1; m >>= 1)      // reduce within 32-lane half
                p += __shfl_xor(p, m, 64);
            g[i] = p + bias;
        }

        float bmax = fmaxf(fmaxf(g[0], g[1]), fmaxf(g[2], g[3]));
        const float m_new = fmaxf(m_run, bmax);
        const float scale = __expf(m_run - m_new);  // 0 on first batch
        m_run = m_new;
        s_run *= scale;
        acc.x *= scale; acc.y *= scale; acc.z *= scale; acc.w *= scale;

        #pragma unroll
        for (int i = 0; i < 4; ++i) {
            const float e = __expf(g[i] - m_new);
            s_run += e;
            acc.x = fmaf(e, f[i].x, acc.x);
            acc.y = fmaf(e, f[i].y, acc.y);
            acc.z = fmaf(e, f[i].z, acc.z);
            acc.w = fmaf(e, f[i].w, acc.w);
        }
        rowp += 8 * D;
    }

    // ---- 2-row steps ----
    for (; r + 2 <= end; r += 2) {
        const float4 f = *reinterpret_cast<const float4*>(rowp);
        float p = f.x * w4.x + f.y * w4.y + f.z * w4.z + f.w * w4.w;
        #pragma unroll
        for (int m = 16; m >= 1; m >>= 1)
            p += __shfl_xor(p, m, 64);
        const float g = p + bias;
        const float m_new = fmaxf(m_run, g);
        const float scale = __expf(m_run - m_new);
        const float e = __expf(g - m_new);
        m_run = m_new;
        s_run = s_run * scale + e;
        acc.x = fmaf(e, f.x, acc.x * scale);
        acc.y = fmaf(e, f.y, acc.y * scale);
        acc.z = fmaf(e, f.z, acc.z * scale);
        acc.w = fmaf(e, f.w, acc.w * scale);
        rowp += 2 * D;
    }

    // ---- final odd row (half 0 only) ----
    if (r < end) {
        float4 f = {0.f, 0.f, 0.f, 0.f};
        if (hr == 0)
            f = *reinterpret_cast<const float4*>(rowp);
        float p = f.x * w4.x + f.y * w4.y + f.z * w4.z + f.w * w4.w;
        #pragma unroll
        for (int m = 16; m >= 1; m >>= 1)
            p += __shfl_xor(p, m, 64);
        if (hr == 0) {
            const float g = p + bias;
            const float m_new = fmaxf(m_run, g);
            const float scale = __expf(m_run - m_new);
            const float e = __expf(g - m_new);
            m_run = m_new;
            s_run = s_run * scale + e;
            acc.x = fmaf(e, f.x, acc.x * scale);
            acc.y = fmaf(e, f.y, acc.y * scale);
            acc.z = fmaf(e, f.z, acc.z * scale);
            acc.w = fmaf(e, f.w, acc.w * scale);
        }
    }

    // ---- flash-style combine across the two halves ----
    const float other_m = __shfl_xor(m_run, 32, 64);
    const float m_tot   = fmaxf(m_run, other_m);
    const float my_s    = __expf(m_run - m_tot);   // 0 if my half is empty

    float sm = s_run * my_s;
    const float s_tot = sm + __shfl_xor(sm, 32, 64);

    float4 a;
    a.x = acc.x * my_s; a.y = acc.y * my_s; a.z = acc.z * my_s; a.w = acc.w * my_s;
    a.x += __shfl_xor(a.x, 32, 64);
    a.y += __shfl_xor(a.y, 32, 64);
    a.z += __shfl_xor(a.z, 32, 64);
    a.w += __shfl_xor(a.w, 32, 64);

    if (hr == 0) {
        const float inv = 1.0f / s_tot;
        float4 o = {a.x * inv, a.y * inv, a.z * inv, a.w * inv};
        *reinterpret_cast<float4*>(out + (size_t)seg * D + 4 * c4) = o;
    }
}

extern "C" void kernel_launch(void* const* d_in, const int* in_sizes, int n_in,
                              void* d_out, int out_size, void* d_ws, size_t ws_size,
                              hipStream_t stream) {
    const float* feat = (const float*)d_in[0];
    const float* Wg   = (const float*)d_in[1];
    const float* bg   = (const float*)d_in[2];
    const int*   seg  = (const int*)d_in[3];
    float*       out  = (float*)d_out;

    const int N = in_sizes[3];      // nodes
    const int B = out_size / D;     // segments

    int* starts = (int*)d_ws;       // ws is ~4 GB, far more than (B+1)*4 bytes
    seg_starts_kernel<<<(B + 1 + NT - 1) / NT, NT, 0, stream>>>(seg, starts, N, B);

    const int segs_per_block = 4;   // one wave each
    gap_wave_kernel<<<(B + segs_per_block - 1) / segs_per_block, NT, 0, stream>>>(
        feat, Wg, bg, starts, out, B);
}

// Round 4
// 199.793 us; speedup vs baseline: 1.5594x; 1.0044x over previous
//
#include <hip/hip_runtime.h>
#include <float.h>

#define D 128
#define NT 256

// Precompute segment start offsets: starts[s] = lower_bound(seg_ids, s), starts[B] = N.
__global__ __launch_bounds__(NT) void seg_starts_kernel(const int* __restrict__ seg_ids,
                                                        int* __restrict__ starts,
                                                        int N, int B) {
    int s = blockIdx.x * blockDim.x + threadIdx.x;
    if (s > B) return;
    if (s == B) { starts[B] = N; return; }
    int lo = 0, hi = N;
    while (lo < hi) { int mid = (lo + hi) >> 1; if (seg_ids[mid] < s) lo = mid + 1; else hi = mid; }
    starts[s] = lo;
}

// One wave per segment. Lane l: row-parity hr = l>>5, cols 4*(l&31)..+3 (float4).
// Independent online-softmax state per 32-lane half; flash-combine at the end.
// Software-pipelined: batch b+1's loads issue before batch b is processed.
__global__ __launch_bounds__(NT, 6) void gap_wave_kernel(const float* __restrict__ feat,
                                                         const float* __restrict__ Wg,
                                                         const float* __restrict__ bg,
                                                         const int* __restrict__ starts,
                                                         float* __restrict__ out,
                                                         int B) {
    const int wid  = threadIdx.x >> 6;
    const int lane = threadIdx.x & 63;
    const int seg  = blockIdx.x * 4 + wid;
    if (seg >= B) return;

    const int hr = lane >> 5;        // row parity this half-wave owns
    const int c4 = lane & 31;        // column group: cols 4*c4 .. 4*c4+3

    const int start = starts[seg];
    const int end   = starts[seg + 1];
    const int n     = end - start;

    if (n <= 0) {
        if (hr == 0) {
            float4 z = {0.f, 0.f, 0.f, 0.f};
            *reinterpret_cast<float4*>(out + (size_t)seg * D + 4 * c4) = z;
        }
        return;
    }

    const float4 w4  = *reinterpret_cast<const float4*>(Wg + 4 * c4);
    const float bias = bg[0];

    float m_run = -FLT_MAX, s_run = 0.0f;
    float4 acc = {0.f, 0.f, 0.f, 0.f};

    // my half's row pointer: rows start+hr, start+hr+2, ...
    const float* rowp = feat + (size_t)(start + hr) * D + 4 * c4;
    const int nfull = n >> 3;        // number of 8-row batches

#define PROCESS_BATCH(F)                                                      \
    do {                                                                      \
        float g[4];                                                           \
        _Pragma("unroll")                                                     \
        for (int i = 0; i < 4; ++i) {                                         \
            float p = (F)[i].x * w4.x + (F)[i].y * w4.y +                     \
                      (F)[i].z * w4.z + (F)[i].w * w4.w;                      \
            _Pragma("unroll")                                                 \
            for (int m = 16; m >= 1; m >>= 1)                                 \
                p += __shfl_xor(p, m, 64);                                    \
            g[i] = p + bias;                                                  \
        }                                                                     \
        float bmax = fmaxf(fmaxf(g[0], g[1]), fmaxf(g[2], g[3]));             \
        const float m_new = fmaxf(m_run, bmax);                               \
        const float scale = __expf(m_run - m_new);                            \
        m_run = m_new;                                                        \
        s_run *= scale;                                                       \
        acc.x *= scale; acc.y *= scale; acc.z *= scale; acc.w *= scale;       \
        _Pragma("unroll")                                                     \
        for (int i = 0; i < 4; ++i) {                                         \
            const float e = __expf(g[i] - m_new);                             \
            s_run += e;                                                       \
            acc.x = fmaf(e, (F)[i].x, acc.x);                                 \
            acc.y = fmaf(e, (F)[i].y, acc.y);                                 \
            acc.z = fmaf(e, (F)[i].z, acc.z);                                 \
            acc.w = fmaf(e, (F)[i].w, acc.w);                                 \
        }                                                                     \
    } while (0)

    if (nfull > 0) {
        float4 f[4];
        #pragma unroll
        for (int i = 0; i < 4; ++i)
            f[i] = *reinterpret_cast<const float4*>(rowp + (size_t)(2 * i) * D);

        for (int b = 1; b < nfull; ++b) {
            rowp += 8 * D;
            float4 fn[4];
            #pragma unroll
            for (int i = 0; i < 4; ++i)       // prefetch batch b before processing b-1
                fn[i] = *reinterpret_cast<const float4*>(rowp + (size_t)(2 * i) * D);

            PROCESS_BATCH(f);

            #pragma unroll
            for (int i = 0; i < 4; ++i) f[i] = fn[i];
        }
        PROCESS_BATCH(f);
        rowp += 8 * D;
    }

    int r = start + nfull * 8;
    // ---- 2-row steps ----
    for (; r + 2 <= end; r += 2) {
        const float4 f = *reinterpret_cast<const float4*>(rowp);
        float p = f.x * w4.x + f.y * w4.y + f.z * w4.z + f.w * w4.w;
        #pragma unroll
        for (int m = 16; m >= 1; m >>= 1)
            p += __shfl_xor(p, m, 64);
        const float g = p + bias;
        const float m_new = fmaxf(m_run, g);
        const float scale = __expf(m_run - m_new);
        const float e = __expf(g - m_new);
        m_run = m_new;
        s_run = s_run * scale + e;
        acc.x = fmaf(e, f.x, acc.x * scale);
        acc.y = fmaf(e, f.y, acc.y * scale);
        acc.z = fmaf(e, f.z, acc.z * scale);
        acc.w = fmaf(e, f.w, acc.w * scale);
        rowp += 2 * D;
    }

    // ---- final odd row (half 0 only) ----
    if (r < end) {
        float4 f = {0.f, 0.f, 0.f, 0.f};
        if (hr == 0)
            f = *reinterpret_cast<const float4*>(rowp);
        float p = f.x * w4.x + f.y * w4.y + f.z * w4.z + f.w * w4.w;
        #pragma unroll
        for (int m = 16; m >= 1; m >>= 1)
            p += __shfl_xor(p, m, 64);
        if (hr == 0) {
            const float g = p + bias;
            const float m_new = fmaxf(m_run, g);
            const float scale = __expf(m_run - m_new);
            const float e = __expf(g - m_new);
            m_run = m_new;
            s_run = s_run * scale + e;
            acc.x = fmaf(e, f.x, acc.x * scale);
            acc.y = fmaf(e, f.y, acc.y * scale);
            acc.z = fmaf(e, f.z, acc.z * scale);
            acc.w = fmaf(e, f.w, acc.w * scale);
        }
    }

    // ---- flash-style combine across the two halves ----
    const float other_m = __shfl_xor(m_run, 32, 64);
    const float m_tot   = fmaxf(m_run, other_m);
    const float my_s    = __expf(m_run - m_tot);   // 0 if my half is empty

    float sm = s_run * my_s;
    const float s_tot = sm + __shfl_xor(sm, 32, 64);

    float4 a;
    a.x = acc.x * my_s; a.y = acc.y * my_s; a.z = acc.z * my_s; a.w = acc.w * my_s;
    a.x += __shfl_xor(a.x, 32, 64);
    a.y += __shfl_xor(a.y, 32, 64);
    a.z += __shfl_xor(a.z, 32, 64);
    a.w += __shfl_xor(a.w, 32, 64);

    if (hr == 0) {
        const float inv = 1.0f / s_tot;
        float4 o = {a.x * inv, a.y * inv, a.z * inv, a.w * inv};
        *reinterpret_cast<float4*>(out + (size_t)seg * D + 4 * c4) = o;
    }
}

extern "C" void kernel_launch(void* const* d_in, const int* in_sizes, int n_in,
                              void* d_out, int out_size, void* d_ws, size_t ws_size,
                              hipStream_t stream) {
    const float* feat = (const float*)d_in[0];
    const float* Wg   = (const float*)d_in[1];
    const float* bg   = (const float*)d_in[2];
    const int*   seg  = (const int*)d_in[3];
    float*       out  = (float*)d_out;

    const int N = in_sizes[3];      // nodes
    const int B = out_size / D;     // segments

    int* starts = (int*)d_ws;       // ws is ~4 GB, far more than (B+1)*4 bytes
    seg_starts_kernel<<<(B + 1 + NT - 1) / NT, NT, 0, stream>>>(seg, starts, N, B);

    const int segs_per_block = 4;   // one wave each
    gap_wave_kernel<<<(B + segs_per_block - 1) / segs_per_block, NT, 0, stream>>>(
        feat, Wg, bg, starts, out, B);
}

// Round 5
// 178.140 us; speedup vs baseline: 1.7490x; 1.1215x over previous
//
#include <hip/hip_runtime.h>
#include <float.h>

#define D 128
#define NT 256

typedef float v4f __attribute__((ext_vector_type(4)));

__device__ inline float4 ntload4(const float* p) {
    v4f v = __builtin_nontemporal_load(reinterpret_cast<const v4f*>(p));
    float4 r; r.x = v.x; r.y = v.y; r.z = v.z; r.w = v.w;
    return r;
}

// Boundary-detection scan: starts[s] = lower_bound(seg_ids, s) for sorted ids.
// Each thread looks at (seg_ids[i-1], seg_ids[i]]; writes starts for every
// segment beginning at i (covers empty segments). Thread N-1 fills the tail.
__global__ __launch_bounds__(NT) void seg_starts_scan(const int* __restrict__ seg_ids,
                                                      int* __restrict__ starts,
                                                      int N, int B) {
    int i = blockIdx.x * blockDim.x + threadIdx.x;
    if (i >= N) return;
    const int cur  = seg_ids[i];
    const int prev = (i == 0) ? -1 : seg_ids[i - 1];
    for (int s = prev + 1; s <= cur; ++s) starts[s] = i;
    if (i == N - 1)
        for (int s = cur + 1; s <= B; ++s) starts[s] = N;
}

// One wave per segment. Lane l: row-parity hr = l>>5, cols 4*(l&31)..+3 (float4).
// Independent online-softmax state per 32-lane half; flash-combine at the end.
// Nontemporal loads: feat is a zero-reuse stream.
__global__ __launch_bounds__(NT, 8) void gap_wave_kernel(const float* __restrict__ feat,
                                                         const float* __restrict__ Wg,
                                                         const float* __restrict__ bg,
                                                         const int* __restrict__ starts,
                                                         float* __restrict__ out,
                                                         int B) {
    const int wid  = threadIdx.x >> 6;
    const int lane = threadIdx.x & 63;
    const int seg  = blockIdx.x * 4 + wid;
    if (seg >= B) return;

    const int hr = lane >> 5;        // row parity this half-wave owns
    const int c4 = lane & 31;        // column group: cols 4*c4 .. 4*c4+3

    const int start = starts[seg];
    const int end   = starts[seg + 1];
    const int n     = end - start;

    if (n <= 0) {
        if (hr == 0) {
            float4 z = {0.f, 0.f, 0.f, 0.f};
            *reinterpret_cast<float4*>(out + (size_t)seg * D + 4 * c4) = z;
        }
        return;
    }

    const float4 w4  = *reinterpret_cast<const float4*>(Wg + 4 * c4);
    const float bias = bg[0];

    float m_run = -FLT_MAX, s_run = 0.0f;
    float4 acc = {0.f, 0.f, 0.f, 0.f};

    // my half's row pointer: rows start+hr, start+hr+2, ...
    const float* rowp = feat + (size_t)(start + hr) * D + 4 * c4;

    int r = start;
    // ---- main loop: 8 rows / iter (4 rows per half), 4 x 16B nt loads ----
    for (; r + 8 <= end; r += 8) {
        float4 f[4];
        #pragma unroll
        for (int i = 0; i < 4; ++i)
            f[i] = ntload4(rowp + (size_t)(2 * i) * D);

        float g[4];
        #pragma unroll
        for (int i = 0; i < 4; ++i) {
            float p = f[i].x * w4.x + f[i].y * w4.y + f[i].z * w4.z + f[i].w * w4.w;
            #pragma unroll
            for (int m = 16; m >= 1; m >>= 1)      // reduce within 32-lane half
                p += __shfl_xor(p, m, 64);
            g[i] = p + bias;
        }

        float bmax = fmaxf(fmaxf(g[0], g[1]), fmaxf(g[2], g[3]));
        const float m_new = fmaxf(m_run, bmax);
        const float scale = __expf(m_run - m_new);  // 0 on first batch
        m_run = m_new;
        s_run *= scale;
        acc.x *= scale; acc.y *= scale; acc.z *= scale; acc.w *= scale;

        #pragma unroll
        for (int i = 0; i < 4; ++i) {
            const float e = __expf(g[i] - m_new);
            s_run += e;
            acc.x = fmaf(e, f[i].x, acc.x);
            acc.y = fmaf(e, f[i].y, acc.y);
            acc.z = fmaf(e, f[i].z, acc.z);
            acc.w = fmaf(e, f[i].w, acc.w);
        }
        rowp += 8 * D;
    }

    // ---- 2-row steps ----
    for (; r + 2 <= end; r += 2) {
        const float4 f = ntload4(rowp);
        float p = f.x * w4.x + f.y * w4.y + f.z * w4.z + f.w * w4.w;
        #pragma unroll
        for (int m = 16; m >= 1; m >>= 1)
            p += __shfl_xor(p, m, 64);
        const float g = p + bias;
        const float m_new = fmaxf(m_run, g);
        const float scale = __expf(m_run - m_new);
        const float e = __expf(g - m_new);
        m_run = m_new;
        s_run = s_run * scale + e;
        acc.x = fmaf(e, f.x, acc.x * scale);
        acc.y = fmaf(e, f.y, acc.y * scale);
        acc.z = fmaf(e, f.z, acc.z * scale);
        acc.w = fmaf(e, f.w, acc.w * scale);
        rowp += 2 * D;
    }

    // ---- final odd row (half 0 only) ----
    if (r < end) {
        float4 f = {0.f, 0.f, 0.f, 0.f};
        if (hr == 0)
            f = ntload4(rowp);
        float p = f.x * w4.x + f.y * w4.y + f.z * w4.z + f.w * w4.w;
        #pragma unroll
        for (int m = 16; m >= 1; m >>= 1)
            p += __shfl_xor(p, m, 64);
        if (hr == 0) {
            const float g = p + bias;
            const float m_new = fmaxf(m_run, g);
            const float scale = __expf(m_run - m_new);
            const float e = __expf(g - m_new);
            m_run = m_new;
            s_run = s_run * scale + e;
            acc.x = fmaf(e, f.x, acc.x * scale);
            acc.y = fmaf(e, f.y, acc.y * scale);
            acc.z = fmaf(e, f.z, acc.z * scale);
            acc.w = fmaf(e, f.w, acc.w * scale);
        }
    }

    // ---- flash-style combine across the two halves ----
    const float other_m = __shfl_xor(m_run, 32, 64);
    const float m_tot   = fmaxf(m_run, other_m);
    const float my_s    = __expf(m_run - m_tot);   // 0 if my half is empty

    float sm = s_run * my_s;
    const float s_tot = sm + __shfl_xor(sm, 32, 64);

    float4 a;
    a.x = acc.x * my_s; a.y = acc.y * my_s; a.z = acc.z * my_s; a.w = acc.w * my_s;
    a.x += __shfl_xor(a.x, 32, 64);
    a.y += __shfl_xor(a.y, 32, 64);
    a.z += __shfl_xor(a.z, 32, 64);
    a.w += __shfl_xor(a.w, 32, 64);

    if (hr == 0) {
        const float inv = 1.0f / s_tot;
        float4 o = {a.x * inv, a.y * inv, a.z * inv, a.w * inv};
        *reinterpret_cast<float4*>(out + (size_t)seg * D + 4 * c4) = o;
    }
}

extern "C" void kernel_launch(void* const* d_in, const int* in_sizes, int n_in,
                              void* d_out, int out_size, void* d_ws, size_t ws_size,
                              hipStream_t stream) {
    const float* feat = (const float*)d_in[0];
    const float* Wg   = (const float*)d_in[1];
    const float* bg   = (const float*)d_in[2];
    const int*   seg  = (const int*)d_in[3];
    float*       out  = (float*)d_out;

    const int N = in_sizes[3];      // nodes
    const int B = out_size / D;     // segments

    int* starts = (int*)d_ws;       // ws is ~4 GB, far more than (B+1)*4 bytes
    seg_starts_scan<<<(N + NT - 1) / NT, NT, 0, stream>>>(seg, starts, N, B);

    const int segs_per_block = 4;   // one wave each
    gap_wave_kernel<<<(B + segs_per_block - 1) / segs_per_block, NT, 0, stream>>>(
        feat, Wg, bg, starts, out, B);
}

// Round 6
// 176.372 us; speedup vs baseline: 1.7665x; 1.0100x over previous
//
#include <hip/hip_runtime.h>
#include <float.h>

#define D 128
#define NT 256

typedef float v4f __attribute__((ext_vector_type(4)));
typedef int   v4i __attribute__((ext_vector_type(4)));

__device__ inline float4 ntload4(const float* p) {
    v4f v = __builtin_nontemporal_load(reinterpret_cast<const v4f*>(p));
    float4 r; r.x = v.x; r.y = v.y; r.z = v.z; r.w = v.w;
    return r;
}
__device__ inline void ntstore4(float* p, float4 v) {
    v4f t; t.x = v.x; t.y = v.y; t.z = v.z; t.w = v.w;
    __builtin_nontemporal_store(t, reinterpret_cast<v4f*>(p));
}

// Boundary-detection scan, 4 ids per thread via int4.
// starts[s] = lower_bound(seg_ids, s); covers empty segments; thread owning
// the last element fills the tail.
__global__ __launch_bounds__(NT) void seg_starts_scan(const int* __restrict__ seg_ids,
                                                      int* __restrict__ starts,
                                                      int N, int B) {
    const int i4 = (blockIdx.x * blockDim.x + threadIdx.x) * 4;
    if (i4 >= N) return;

    int ids[5];
    ids[0] = (i4 == 0) ? -1 : seg_ids[i4 - 1];
    int cnt;
    if (i4 + 4 <= N) {
        v4i c = __builtin_nontemporal_load(reinterpret_cast<const v4i*>(seg_ids + i4));
        ids[1] = c.x; ids[2] = c.y; ids[3] = c.z; ids[4] = c.w;
        cnt = 4;
    } else {
        cnt = N - i4;
        for (int j = 0; j < cnt; ++j) ids[1 + j] = seg_ids[i4 + j];
    }

    for (int j = 0; j < cnt; ++j)
        for (int s = ids[j] + 1; s <= ids[j + 1]; ++s) starts[s] = i4 + j;

    if (i4 + cnt == N)
        for (int s = ids[cnt] + 1; s <= B; ++s) starts[s] = N;
}

// One wave per segment. Lane l: row-parity hr = l>>5, cols 4*(l&31)..+3 (float4).
// Independent online-softmax state per 32-lane half; flash-combine at the end.
// Nontemporal loads/stores: feat and out are zero-reuse streams.
__global__ __launch_bounds__(NT, 8) void gap_wave_kernel(const float* __restrict__ feat,
                                                         const float* __restrict__ Wg,
                                                         const float* __restrict__ bg,
                                                         const int* __restrict__ starts,
                                                         float* __restrict__ out,
                                                         int B) {
    const int wid  = threadIdx.x >> 6;
    const int lane = threadIdx.x & 63;
    const int seg  = blockIdx.x * 4 + wid;
    if (seg >= B) return;

    const int hr = lane >> 5;        // row parity this half-wave owns
    const int c4 = lane & 31;        // column group: cols 4*c4 .. 4*c4+3

    const int start = starts[seg];
    const int end   = starts[seg + 1];
    const int n     = end - start;

    if (n <= 0) {
        if (hr == 0) {
            float4 z = {0.f, 0.f, 0.f, 0.f};
            ntstore4(out + (size_t)seg * D + 4 * c4, z);
        }
        return;
    }

    const float4 w4  = *reinterpret_cast<const float4*>(Wg + 4 * c4);
    const float bias = bg[0];

    float m_run = -FLT_MAX, s_run = 0.0f;
    float4 acc = {0.f, 0.f, 0.f, 0.f};

    // my half's row pointer: rows start+hr, start+hr+2, ...
    const float* rowp = feat + (size_t)(start + hr) * D + 4 * c4;

    int r = start;
    // ---- main loop: 8 rows / iter (4 rows per half), 4 x 16B nt loads ----
    for (; r + 8 <= end; r += 8) {
        float4 f[4];
        #pragma unroll
        for (int i = 0; i < 4; ++i)
            f[i] = ntload4(rowp + (size_t)(2 * i) * D);

        float g[4];
        #pragma unroll
        for (int i = 0; i < 4; ++i) {
            float p = f[i].x * w4.x + f[i].y * w4.y + f[i].z * w4.z + f[i].w * w4.w;
            #pragma unroll
            for (int m = 16; m >= 1; m >>= 1)      // reduce within 32-lane half
                p += __shfl_xor(p, m, 64);
            g[i] = p + bias;
        }

        float bmax = fmaxf(fmaxf(g[0], g[1]), fmaxf(g[2], g[3]));
        const float m_new = fmaxf(m_run, bmax);
        const float scale = __expf(m_run - m_new);  // 0 on first batch
        m_run = m_new;
        s_run *= scale;
        acc.x *= scale; acc.y *= scale; acc.z *= scale; acc.w *= scale;

        #pragma unroll
        for (int i = 0; i < 4; ++i) {
            const float e = __expf(g[i] - m_new);
            s_run += e;
            acc.x = fmaf(e, f[i].x, acc.x);
            acc.y = fmaf(e, f[i].y, acc.y);
            acc.z = fmaf(e, f[i].z, acc.z);
            acc.w = fmaf(e, f[i].w, acc.w);
        }
        rowp += 8 * D;
    }

    // ---- 2-row steps ----
    for (; r + 2 <= end; r += 2) {
        const float4 f = ntload4(rowp);
        float p = f.x * w4.x + f.y * w4.y + f.z * w4.z + f.w * w4.w;
        #pragma unroll
        for (int m = 16; m >= 1; m >>= 1)
            p += __shfl_xor(p, m, 64);
        const float g = p + bias;
        const float m_new = fmaxf(m_run, g);
        const float scale = __expf(m_run - m_new);
        const float e = __expf(g - m_new);
        m_run = m_new;
        s_run = s_run * scale + e;
        acc.x = fmaf(e, f.x, acc.x * scale);
        acc.y = fmaf(e, f.y, acc.y * scale);
        acc.z = fmaf(e, f.z, acc.z * scale);
        acc.w = fmaf(e, f.w, acc.w * scale);
        rowp += 2 * D;
    }

    // ---- final odd row (half 0 only) ----
    if (r < end) {
        float4 f = {0.f, 0.f, 0.f, 0.f};
        if (hr == 0)
            f = ntload4(rowp);
        float p = f.x * w4.x + f.y * w4.y + f.z * w4.z + f.w * w4.w;
        #pragma unroll
        for (int m = 16; m >= 1; m >>= 1)
            p += __shfl_xor(p, m, 64);
        if (hr == 0) {
            const float g = p + bias;
            const float m_new = fmaxf(m_run, g);
            const float scale = __expf(m_run - m_new);
            const float e = __expf(g - m_new);
            m_run = m_new;
            s_run = s_run * scale + e;
            acc.x = fmaf(e, f.x, acc.x * scale);
            acc.y = fmaf(e, f.y, acc.y * scale);
            acc.z = fmaf(e, f.z, acc.z * scale);
            acc.w = fmaf(e, f.w, acc.w * scale);
        }
    }

    // ---- flash-style combine across the two halves ----
    const float other_m = __shfl_xor(m_run, 32, 64);
    const float m_tot   = fmaxf(m_run, other_m);
    const float my_s    = __expf(m_run - m_tot);   // 0 if my half is empty

    float sm = s_run * my_s;
    const float s_tot = sm + __shfl_xor(sm, 32, 64);

    float4 a;
    a.x = acc.x * my_s; a.y = acc.y * my_s; a.z = acc.z * my_s; a.w = acc.w * my_s;
    a.x += __shfl_xor(a.x, 32, 64);
    a.y += __shfl_xor(a.y, 32, 64);
    a.z += __shfl_xor(a.z, 32, 64);
    a.w += __shfl_xor(a.w, 32, 64);

    if (hr == 0) {
        const float inv = 1.0f / s_tot;
        float4 o = {a.x * inv, a.y * inv, a.z * inv, a.w * inv};
        ntstore4(out + (size_t)seg * D + 4 * c4, o);
    }
}

extern "C" void kernel_launch(void* const* d_in, const int* in_sizes, int n_in,
                              void* d_out, int out_size, void* d_ws, size_t ws_size,
                              hipStream_t stream) {
    const float* feat = (const float*)d_in[0];
    const float* Wg   = (const float*)d_in[1];
    const float* bg   = (const float*)d_in[2];
    const int*   seg  = (const int*)d_in[3];
    float*       out  = (float*)d_out;

    const int N = in_sizes[3];      // nodes
    const int B = out_size / D;     // segments

    int* starts = (int*)d_ws;       // ws is ~4 GB, far more than (B+1)*4 bytes
    const int nquads = (N + 3) / 4;
    seg_starts_scan<<<(nquads + NT - 1) / NT, NT, 0, stream>>>(seg, starts, N, B);

    const int segs_per_block = 4;   // one wave each
    gap_wave_kernel<<<(B + segs_per_block - 1) / segs_per_block, NT, 0, stream>>>(
        feat, Wg, bg, starts, out, B);
}